// Round 2
// baseline (1449.471 us; speedup 1.0000x reference)
//
#include <hip/hip_runtime.h>
#include <cstdint>
#include <cstddef>

#define T_ 512
#define B_ 128
#define D_ 256
#define H_ 512
#define C_ 10

typedef float  f32x4 __attribute__((ext_vector_type(4)));
typedef short  s16x8 __attribute__((ext_vector_type(8)));
typedef _Float16 v2h __attribute__((ext_vector_type(2)));

static __device__ __forceinline__ unsigned short f2bf(float f) {
    unsigned u = __builtin_bit_cast(unsigned, f);
    unsigned r = u + 0x7FFFu + ((u >> 16) & 1u);   // round-to-nearest-even
    return (unsigned short)(r >> 16);
}

static __device__ __forceinline__ float dot2f(v2h a, v2h b, float c) {
#if __has_builtin(__builtin_amdgcn_fdot2)
    return __builtin_amdgcn_fdot2(a, b, c, false);
#else
    return c + (float)a.x * (float)b.x + (float)a.y * (float)b.y;
#endif
}

// ---------------------------------------------------------------------------
// Prep 0: W_hx [256,512] f32 -> W_hx^T [512,256] bf16 (col-major-of-B for MFMA)
// ---------------------------------------------------------------------------
__global__ void k_whxT(const float* __restrict__ Whx, unsigned short* __restrict__ WhxT) {
    int idx = blockIdx.x * 256 + threadIdx.x;     // 131072 total
    int n = idx >> 8;                             // 0..511
    int k = idx & 255;                            // 0..255
    WhxT[n * 256 + k] = f2bf(Whx[k * 512 + n]);   // coalesced writes
}

// ---------------------------------------------------------------------------
// Prep 1: W_hh [512,512] f32 -> WpkT [256][512] u32, WpkT[r][j] = pack_f16(W[2r][j], W[2r+1][j])
// ---------------------------------------------------------------------------
__global__ void k_wpkT(const float* __restrict__ Whh, unsigned* __restrict__ WpkT) {
    int idx = blockIdx.x * 256 + threadIdx.x;     // 131072 total
    int r = idx >> 9;                             // 0..255
    int j = idx & 511;                            // 0..511
    _Float16 lo = (_Float16)Whh[(2 * r) * 512 + j];
    _Float16 hi = (_Float16)Whh[(2 * r + 1) * 512 + j];
    WpkT[r * 512 + j] = (unsigned)__builtin_bit_cast(unsigned short, lo) |
                        ((unsigned)__builtin_bit_cast(unsigned short, hi) << 16);
}

// ---------------------------------------------------------------------------
// Phase 1: Z = x @ W_hx + b_h      [65536,256] @ [256,512] -> f16 Z
// 128x128 tile, 4 waves (2x2), mfma_f32_16x16x32_bf16, reg-staged LDS tiles.
// ---------------------------------------------------------------------------
__global__ void __launch_bounds__(256) k_gemm1(const float* __restrict__ x,
                                               const unsigned short* __restrict__ WhxT,
                                               const float* __restrict__ bh,
                                               _Float16* __restrict__ Zh) {
    __shared__ unsigned short Asm[128 * 32];   // [row][k] bf16
    __shared__ unsigned short Bsm[128 * 32];   // [col][k] bf16
    const int tid = threadIdx.x;
    const int bid = blockIdx.x;
    const int nt = bid & 3, mt = bid >> 2;
    const int r0 = mt * 128, n0 = nt * 128;
    const int w  = tid >> 6, l = tid & 63;
    const int wm = (w >> 1) * 64, wn = (w & 1) * 64;
    const int lr = l & 15, lk = (l >> 4) * 8;

    const int arow = tid >> 2, akc = (tid & 3) * 8;   // A staging: 2 halves x 8 f32 per thread
    const int bcol = tid >> 1, bkc = (tid & 1) * 16;  // B staging: 32B of bf16 per thread

    f32x4 acc[4][4] = {};

    for (int kk = 0; kk < 256; kk += 32) {
        // ---- stage A (f32 -> bf16), FULL 128 rows: two 64-row halves ----
#pragma unroll
        for (int half = 0; half < 2; ++half) {
            const int r = arow + half * 64;
            const float* ap = x + (size_t)(r0 + r) * 256 + kk + akc;
            float4 f0 = *(const float4*)ap;
            float4 f1 = *(const float4*)(ap + 4);
            uint4 av;
            av.x = (unsigned)f2bf(f0.x) | ((unsigned)f2bf(f0.y) << 16);
            av.y = (unsigned)f2bf(f0.z) | ((unsigned)f2bf(f0.w) << 16);
            av.z = (unsigned)f2bf(f1.x) | ((unsigned)f2bf(f1.y) << 16);
            av.w = (unsigned)f2bf(f1.z) | ((unsigned)f2bf(f1.w) << 16);
            *(uint4*)&Asm[r * 32 + akc] = av;
        }
        // ---- stage B (already bf16, transposed layout) ----
        const unsigned short* bsrc = WhxT + (size_t)(n0 + bcol) * 256 + kk + bkc;
        uint4 bv0 = *(const uint4*)bsrc;
        uint4 bv1 = *(const uint4*)(bsrc + 8);
        *(uint4*)&Bsm[bcol * 32 + bkc] = bv0;
        *(uint4*)&Bsm[bcol * 32 + bkc + 8] = bv1;
        __syncthreads();

        s16x8 af[4], bf[4];
#pragma unroll
        for (int mi = 0; mi < 4; ++mi)
            af[mi] = *(const s16x8*)&Asm[(wm + mi * 16 + lr) * 32 + lk];
#pragma unroll
        for (int ni = 0; ni < 4; ++ni)
            bf[ni] = *(const s16x8*)&Bsm[(wn + ni * 16 + lr) * 32 + lk];
#pragma unroll
        for (int mi = 0; mi < 4; ++mi)
#pragma unroll
            for (int ni = 0; ni < 4; ++ni)
                acc[mi][ni] = __builtin_amdgcn_mfma_f32_16x16x32_bf16(af[mi], bf[ni], acc[mi][ni], 0, 0, 0);
        __syncthreads();
    }

    // epilogue: C/D layout col = lane&15, row = (lane>>4)*4 + e
#pragma unroll
    for (int mi = 0; mi < 4; ++mi)
#pragma unroll
        for (int ni = 0; ni < 4; ++ni) {
            int col = n0 + wn + ni * 16 + lr;
            float bhv = bh[col];
#pragma unroll
            for (int e = 0; e < 4; ++e) {
                int row = r0 + wm + mi * 16 + (l >> 4) * 4 + e;
                Zh[(size_t)row * 512 + col] = (_Float16)(acc[mi][ni][e] + bhv);
            }
        }
}

// ---------------------------------------------------------------------------
// Phase 2: sequential recurrence. 128 WGs (one per batch row), 512 threads
// (one per hidden column). W_hh column j stationary per thread:
//   k in [0,384): 192 packed-f16 VGPRs;  k in [384,512): 128 KiB LDS.
// h kept as packed f16 in LDS, read wave-uniform (broadcast). 2 barriers/step.
// ---------------------------------------------------------------------------
__global__ void __launch_bounds__(512, 2) k_rnn(const unsigned* __restrict__ WpkT,
                                                const _Float16* __restrict__ Zh,
                                                float* __restrict__ hf) {
    __shared__ uint4 Wl4[8192];    // 128 KiB: per-thread W k in [384,512)
    __shared__ uint4 h4s[64];      // 1 KiB: h as 512 packed f16

    const int j  = threadIdx.x;        // hidden column
    const int b  = blockIdx.x;         // batch row
    const int wv = j >> 6, ln = j & 63;

    // ---- load stationary weights ----
    v2h wreg[192];
#pragma unroll
    for (int r = 0; r < 192; ++r)
        wreg[r] = __builtin_bit_cast(v2h, WpkT[r * 512 + j]);

#pragma unroll
    for (int rb = 0; rb < 16; ++rb) {
        uint4 w4;
        w4.x = WpkT[(192 + rb * 4 + 0) * 512 + j];
        w4.y = WpkT[(192 + rb * 4 + 1) * 512 + j];
        w4.z = WpkT[(192 + rb * 4 + 2) * 512 + j];
        w4.w = WpkT[(192 + rb * 4 + 3) * 512 + j];
        Wl4[(wv * 16 + rb) * 64 + ln] = w4;
    }
    ((_Float16*)h4s)[j] = (_Float16)0.0f;   // h0 = 0
    __syncthreads();

    float hv = 0.0f;
    for (int t = 0; t < T_; ++t) {
        float zc = (float)Zh[((size_t)t * B_ + b) * H_ + j];   // issued early, used late
        float a0 = 0.f, a1 = 0.f, a2 = 0.f, a3 = 0.f;
#pragma unroll
        for (int rb = 0; rb < 48; ++rb) {                      // k in [0,384), W from regs
            uint4 hh = h4s[rb];                                // wave-uniform broadcast
            a0 = dot2f(wreg[rb * 4 + 0], __builtin_bit_cast(v2h, hh.x), a0);
            a1 = dot2f(wreg[rb * 4 + 1], __builtin_bit_cast(v2h, hh.y), a1);
            a2 = dot2f(wreg[rb * 4 + 2], __builtin_bit_cast(v2h, hh.z), a2);
            a3 = dot2f(wreg[rb * 4 + 3], __builtin_bit_cast(v2h, hh.w), a3);
        }
#pragma unroll
        for (int rb = 0; rb < 16; ++rb) {                      // k in [384,512), W from LDS
            uint4 ww = Wl4[(wv * 16 + rb) * 64 + ln];
            uint4 hh = h4s[48 + rb];
            a0 = dot2f(__builtin_bit_cast(v2h, ww.x), __builtin_bit_cast(v2h, hh.x), a0);
            a1 = dot2f(__builtin_bit_cast(v2h, ww.y), __builtin_bit_cast(v2h, hh.y), a1);
            a2 = dot2f(__builtin_bit_cast(v2h, ww.z), __builtin_bit_cast(v2h, hh.z), a2);
            a3 = dot2f(__builtin_bit_cast(v2h, ww.w), __builtin_bit_cast(v2h, hh.w), a3);
        }
        float s = (a0 + a1) + (a2 + a3) + zc;
        float e = __expf(2.0f * s);                            // tanh(s) = 1 - 2/(e^{2s}+1)
        hv = 1.0f - 2.0f / (e + 1.0f);
        __syncthreads();                                       // all reads of h done
        ((_Float16*)h4s)[j] = (_Float16)hv;
        __syncthreads();                                       // h_new visible
    }
    hf[b * H_ + j] = hv;
}

// ---------------------------------------------------------------------------
// Phase 3: out = h_final @ W_ph + b_p   [128,512]@[512,10]
// ---------------------------------------------------------------------------
__global__ void k_out(const float* __restrict__ hf, const float* __restrict__ Wph,
                      const float* __restrict__ bp, float* __restrict__ out) {
    __shared__ float red[160];
    int b = blockIdx.x, t = threadIdx.x;
    if (t < 160) {
        int c = t >> 4, ks = (t & 15) * 32;
        float s = 0.f;
        for (int u = 0; u < 32; ++u)
            s += hf[b * H_ + ks + u] * Wph[(ks + u) * C_ + c];
        red[t] = s;
    }
    __syncthreads();
    if (t < C_) {
        float s = bp[t];
        for (int i = 0; i < 16; ++i) s += red[t * 16 + i];
        out[b * C_ + t] = s;
    }
}

// ---------------------------------------------------------------------------
extern "C" void kernel_launch(void* const* d_in, const int* in_sizes, int n_in,
                              void* d_out, int out_size, void* d_ws, size_t ws_size,
                              hipStream_t stream) {
    const float* x   = (const float*)d_in[0];   // [512,128,256]
    const float* Whx = (const float*)d_in[1];   // [256,512]
    const float* Whh = (const float*)d_in[2];   // [512,512]
    const float* Wph = (const float*)d_in[3];   // [512,10]
    const float* bh  = (const float*)d_in[4];   // [512]
    const float* bp  = (const float*)d_in[5];   // [10]
    float* out = (float*)d_out;                 // [128,10] f32

    char* ws = (char*)d_ws;
    unsigned short* WhxT = (unsigned short*)(ws);                    // 256 KiB
    unsigned*       WpkT = (unsigned*)(ws + 262144);                 // 512 KiB
    _Float16*       Zh   = (_Float16*)(ws + 786432);                 // 64 MiB
    float*          hf   = (float*)(ws + 786432 + 67108864);         // 256 KiB

    hipLaunchKernelGGL(k_whxT,  dim3(512),  dim3(256), 0, stream, Whx, WhxT);
    hipLaunchKernelGGL(k_wpkT,  dim3(512),  dim3(256), 0, stream, Whh, WpkT);
    hipLaunchKernelGGL(k_gemm1, dim3(2048), dim3(256), 0, stream, x, WhxT, bh, Zh);
    hipLaunchKernelGGL(k_rnn,   dim3(128),  dim3(512), 0, stream, WpkT, Zh, hf);
    hipLaunchKernelGGL(k_out,   dim3(128),  dim3(256), 0, stream, hf, Wph, bp, out);
}

// Round 3
// 1181.372 us; speedup vs baseline: 1.2269x; 1.2269x over previous
//
#include <hip/hip_runtime.h>
#include <cstdint>
#include <cstddef>

#define T_ 512
#define B_ 128
#define D_ 256
#define H_ 512
#define C_ 10

// weight-pair split: pairs [0,180) in VGPRs, pairs [180,256) in LDS (19 uint4/thread)
#define NPQ_REG 45   // 180 pairs = 45 groups of 4
#define NPQ_LDS 19   // 76 pairs  = 19 groups of 4

typedef float  f32x4 __attribute__((ext_vector_type(4)));
typedef short  s16x8 __attribute__((ext_vector_type(8)));
typedef _Float16 v2h __attribute__((ext_vector_type(2)));

static __device__ __forceinline__ unsigned short f2bf(float f) {
    unsigned u = __builtin_bit_cast(unsigned, f);
    unsigned r = u + 0x7FFFu + ((u >> 16) & 1u);   // round-to-nearest-even
    return (unsigned short)(r >> 16);
}

static __device__ __forceinline__ float dot2f(v2h a, v2h b, float c) {
#if __has_builtin(__builtin_amdgcn_fdot2)
    return __builtin_amdgcn_fdot2(a, b, c, false);
#else
    return c + (float)a.x * (float)b.x + (float)a.y * (float)b.y;
#endif
}

static __device__ __forceinline__ v2h rl(unsigned v, int lane) {
    return __builtin_bit_cast(v2h, (unsigned)__builtin_amdgcn_readlane(v, lane));
}

// ---------------------------------------------------------------------------
// Prep 0: W_hx [256,512] f32 -> W_hx^T [512,256] bf16
// ---------------------------------------------------------------------------
__global__ void k_whxT(const float* __restrict__ Whx, unsigned short* __restrict__ WhxT) {
    int idx = blockIdx.x * 256 + threadIdx.x;
    int n = idx >> 8;
    int k = idx & 255;
    WhxT[n * 256 + k] = f2bf(Whx[k * 512 + n]);
}

// ---------------------------------------------------------------------------
// Prep 1: W_hh [512,512] f32 -> WpkT [256][512] u32 packed-f16 row pairs
// ---------------------------------------------------------------------------
__global__ void k_wpkT(const float* __restrict__ Whh, unsigned* __restrict__ WpkT) {
    int idx = blockIdx.x * 256 + threadIdx.x;
    int r = idx >> 9;
    int j = idx & 511;
    _Float16 lo = (_Float16)Whh[(2 * r) * 512 + j];
    _Float16 hi = (_Float16)Whh[(2 * r + 1) * 512 + j];
    WpkT[r * 512 + j] = (unsigned)__builtin_bit_cast(unsigned short, lo) |
                        ((unsigned)__builtin_bit_cast(unsigned short, hi) << 16);
}

// ---------------------------------------------------------------------------
// Phase 1: Z = x @ W_hx + b_h  ->  f16 Zh [T*B, H]
// ---------------------------------------------------------------------------
__global__ void __launch_bounds__(256) k_gemm1(const float* __restrict__ x,
                                               const unsigned short* __restrict__ WhxT,
                                               const float* __restrict__ bh,
                                               _Float16* __restrict__ Zh) {
    __shared__ unsigned short Asm[128 * 32];
    __shared__ unsigned short Bsm[128 * 32];
    const int tid = threadIdx.x;
    const int bid = blockIdx.x;
    const int nt = bid & 3, mt = bid >> 2;
    const int r0 = mt * 128, n0 = nt * 128;
    const int w  = tid >> 6, l = tid & 63;
    const int wm = (w >> 1) * 64, wn = (w & 1) * 64;
    const int lr = l & 15, lk = (l >> 4) * 8;

    const int arow = tid >> 2, akc = (tid & 3) * 8;
    const int bcol = tid >> 1, bkc = (tid & 1) * 16;

    f32x4 acc[4][4] = {};

    for (int kk = 0; kk < 256; kk += 32) {
#pragma unroll
        for (int half = 0; half < 2; ++half) {
            const int r = arow + half * 64;
            const float* ap = x + (size_t)(r0 + r) * 256 + kk + akc;
            float4 f0 = *(const float4*)ap;
            float4 f1 = *(const float4*)(ap + 4);
            uint4 av;
            av.x = (unsigned)f2bf(f0.x) | ((unsigned)f2bf(f0.y) << 16);
            av.y = (unsigned)f2bf(f0.z) | ((unsigned)f2bf(f0.w) << 16);
            av.z = (unsigned)f2bf(f1.x) | ((unsigned)f2bf(f1.y) << 16);
            av.w = (unsigned)f2bf(f1.z) | ((unsigned)f2bf(f1.w) << 16);
            *(uint4*)&Asm[r * 32 + akc] = av;
        }
        const unsigned short* bsrc = WhxT + (size_t)(n0 + bcol) * 256 + kk + bkc;
        uint4 bv0 = *(const uint4*)bsrc;
        uint4 bv1 = *(const uint4*)(bsrc + 8);
        *(uint4*)&Bsm[bcol * 32 + bkc] = bv0;
        *(uint4*)&Bsm[bcol * 32 + bkc + 8] = bv1;
        __syncthreads();

        s16x8 af[4], bf[4];
#pragma unroll
        for (int mi = 0; mi < 4; ++mi)
            af[mi] = *(const s16x8*)&Asm[(wm + mi * 16 + lr) * 32 + lk];
#pragma unroll
        for (int ni = 0; ni < 4; ++ni)
            bf[ni] = *(const s16x8*)&Bsm[(wn + ni * 16 + lr) * 32 + lk];
#pragma unroll
        for (int mi = 0; mi < 4; ++mi)
#pragma unroll
            for (int ni = 0; ni < 4; ++ni)
                acc[mi][ni] = __builtin_amdgcn_mfma_f32_16x16x32_bf16(af[mi], bf[ni], acc[mi][ni], 0, 0, 0);
        __syncthreads();
    }

#pragma unroll
    for (int mi = 0; mi < 4; ++mi)
#pragma unroll
        for (int ni = 0; ni < 4; ++ni) {
            int col = n0 + wn + ni * 16 + lr;
            float bhv = bh[col];
#pragma unroll
            for (int e = 0; e < 4; ++e) {
                int row = r0 + wm + mi * 16 + (l >> 4) * 4 + e;
                Zh[(size_t)row * 512 + col] = (_Float16)(acc[mi][ni][e] + bhv);
            }
        }
}

// ---------------------------------------------------------------------------
// Phase 2: recurrence. 128 WGs x 512 threads (thread = hidden column j).
// W_hh column j: pairs [0,180) in VGPRs, pairs [180,256) in LDS.
// h: double-buffered packed-f16 in LDS. Per wave per step: ONE ds_read_b128
// pulls all 256 h-pairs (lane l holds pairs 4l..4l+3); h-pair p is broadcast
// to the wave via v_readlane (VALU pipe) -> SGPR operand of v_dot2_f32_f16.
// One barrier per step.
// ---------------------------------------------------------------------------
__global__ void __launch_bounds__(512, 2) k_rnn(const unsigned* __restrict__ WpkT,
                                                const _Float16* __restrict__ Zh,
                                                float* __restrict__ hf) {
    __shared__ uint4    Wl4[NPQ_LDS * 512];  // 152 KiB: pairs [180,256) x 512 cols
    __shared__ unsigned hbuf[2][256];        // 2 KiB: h as packed f16, double-buffered

    const int j = threadIdx.x;     // hidden column
    const int b = blockIdx.x;      // batch row
    const int l = j & 63;          // lane in wave

    // ---- stationary weights: pairs [0,180) to VGPRs ----
    v2h wreg[NPQ_REG * 4];
#pragma unroll
    for (int p = 0; p < NPQ_REG * 4; ++p)
        wreg[p] = __builtin_bit_cast(v2h, WpkT[p * 512 + j]);

    // ---- pairs [180,256) to LDS ----
#pragma unroll
    for (int rb = 0; rb < NPQ_LDS; ++rb) {
        uint4 w4;
        w4.x = WpkT[(NPQ_REG * 4 + rb * 4 + 0) * 512 + j];
        w4.y = WpkT[(NPQ_REG * 4 + rb * 4 + 1) * 512 + j];
        w4.z = WpkT[(NPQ_REG * 4 + rb * 4 + 2) * 512 + j];
        w4.w = WpkT[(NPQ_REG * 4 + rb * 4 + 3) * 512 + j];
        Wl4[rb * 512 + j] = w4;
    }
    ((_Float16*)hbuf[0])[j] = (_Float16)0.0f;   // h0 = 0
    __syncthreads();

    const _Float16* zrow = Zh + (size_t)b * H_ + j;   // stride T-step = B_*H_
    float zc = (float)zrow[0];
    float hv = 0.0f;
    int cur = 0;

    for (int t = 0; t < T_; ++t) {
        // prefetch next step's z (clamped; uniform select)
        int tn = (t + 1 < T_) ? t + 1 : t;
        float zn = (float)zrow[(size_t)tn * (B_ * H_)];

        // one LDS read per wave: lane l gets h-pairs 4l..4l+3
        uint4 hv4 = ((const uint4*)hbuf[cur])[l];

        float a0 = 0.f, a1 = 0.f, a2 = 0.f, a3 = 0.f;
#pragma unroll
        for (int q = 0; q < NPQ_REG; ++q) {            // pairs [0,180), W in VGPR
            a0 = dot2f(wreg[q * 4 + 0], rl(hv4.x, q), a0);
            a1 = dot2f(wreg[q * 4 + 1], rl(hv4.y, q), a1);
            a2 = dot2f(wreg[q * 4 + 2], rl(hv4.z, q), a2);
            a3 = dot2f(wreg[q * 4 + 3], rl(hv4.w, q), a3);
        }
#pragma unroll
        for (int rb = 0; rb < NPQ_LDS; ++rb) {         // pairs [180,256), W in LDS
            uint4 w4 = Wl4[rb * 512 + j];
            const int q = NPQ_REG + rb;
            a0 = dot2f(__builtin_bit_cast(v2h, w4.x), rl(hv4.x, q), a0);
            a1 = dot2f(__builtin_bit_cast(v2h, w4.y), rl(hv4.y, q), a1);
            a2 = dot2f(__builtin_bit_cast(v2h, w4.z), rl(hv4.z, q), a2);
            a3 = dot2f(__builtin_bit_cast(v2h, w4.w), rl(hv4.w, q), a3);
        }
        float s = (a0 + a1) + (a2 + a3) + zc;
        float e = __expf(2.0f * s);                    // tanh(s) = 1 - 2/(e^{2s}+1)
        hv = 1.0f - 2.0f / (e + 1.0f);

        ((_Float16*)hbuf[cur ^ 1])[j] = (_Float16)hv;  // write NEW h to other buffer
        __syncthreads();                               // new h visible; old reads done
        cur ^= 1;
        zc = zn;
    }
    hf[b * H_ + j] = hv;
}

// ---------------------------------------------------------------------------
// Phase 3: out = h_final @ W_ph + b_p   [128,512]@[512,10]
// ---------------------------------------------------------------------------
__global__ void k_out(const float* __restrict__ hf, const float* __restrict__ Wph,
                      const float* __restrict__ bp, float* __restrict__ out) {
    __shared__ float red[160];
    int b = blockIdx.x, t = threadIdx.x;
    if (t < 160) {
        int c = t >> 4, ks = (t & 15) * 32;
        float s = 0.f;
        for (int u = 0; u < 32; ++u)
            s += hf[b * H_ + ks + u] * Wph[(ks + u) * C_ + c];
        red[t] = s;
    }
    __syncthreads();
    if (t < C_) {
        float s = bp[t];
        for (int i = 0; i < 16; ++i) s += red[t * 16 + i];
        out[b * C_ + t] = s;
    }
}

// ---------------------------------------------------------------------------
extern "C" void kernel_launch(void* const* d_in, const int* in_sizes, int n_in,
                              void* d_out, int out_size, void* d_ws, size_t ws_size,
                              hipStream_t stream) {
    const float* x   = (const float*)d_in[0];
    const float* Whx = (const float*)d_in[1];
    const float* Whh = (const float*)d_in[2];
    const float* Wph = (const float*)d_in[3];
    const float* bh  = (const float*)d_in[4];
    const float* bp  = (const float*)d_in[5];
    float* out = (float*)d_out;

    char* ws = (char*)d_ws;
    unsigned short* WhxT = (unsigned short*)(ws);                    // 256 KiB
    unsigned*       WpkT = (unsigned*)(ws + 262144);                 // 512 KiB
    _Float16*       Zh   = (_Float16*)(ws + 786432);                 // 64 MiB
    float*          hf   = (float*)(ws + 786432 + 67108864);         // 256 KiB

    hipLaunchKernelGGL(k_whxT,  dim3(512),  dim3(256), 0, stream, Whx, WhxT);
    hipLaunchKernelGGL(k_wpkT,  dim3(512),  dim3(256), 0, stream, Whh, WpkT);
    hipLaunchKernelGGL(k_gemm1, dim3(2048), dim3(256), 0, stream, x, WhxT, bh, Zh);
    hipLaunchKernelGGL(k_rnn,   dim3(128),  dim3(512), 0, stream, WpkT, Zh, hf);
    hipLaunchKernelGGL(k_out,   dim3(128),  dim3(256), 0, stream, hf, Wph, bp, out);
}

// Round 4
// 1126.959 us; speedup vs baseline: 1.2862x; 1.0483x over previous
//
#include <hip/hip_runtime.h>
#include <cstdint>
#include <cstddef>

#define T_ 512
#define B_ 128
#define D_ 256
#define H_ 512
#define C_ 10

// weight-pair split: 64 q-groups of 4 pairs; groups [0,48) in VGPRs (192 pairs),
// groups [48,64) in LDS (64 pairs, 128 KiB)
#define NQ_REG 48
#define NQ_LDS 16

typedef float  f32x4 __attribute__((ext_vector_type(4)));
typedef short  s16x8 __attribute__((ext_vector_type(8)));
typedef _Float16 v2h __attribute__((ext_vector_type(2)));

static __device__ __forceinline__ unsigned short f2bf(float f) {
    unsigned u = __builtin_bit_cast(unsigned, f);
    unsigned r = u + 0x7FFFu + ((u >> 16) & 1u);   // round-to-nearest-even
    return (unsigned short)(r >> 16);
}

static __device__ __forceinline__ float dot2f(v2h a, v2h b, float c) {
#if __has_builtin(__builtin_amdgcn_fdot2)
    return __builtin_amdgcn_fdot2(a, b, c, false);
#else
    return c + (float)a.x * (float)b.x + (float)a.y * (float)b.y;
#endif
}

static __device__ __forceinline__ v2h rl(unsigned v, int lane) {
    return __builtin_bit_cast(v2h, (unsigned)__builtin_amdgcn_readlane(v, lane));
}
static __device__ __forceinline__ v2h bc(unsigned v) {
    return __builtin_bit_cast(v2h, v);
}

// ---------------------------------------------------------------------------
// Prep 0: W_hx [256,512] f32 -> W_hx^T [512,256] bf16
// ---------------------------------------------------------------------------
__global__ void k_whxT(const float* __restrict__ Whx, unsigned short* __restrict__ WhxT) {
    int idx = blockIdx.x * 256 + threadIdx.x;
    int n = idx >> 8;
    int k = idx & 255;
    WhxT[n * 256 + k] = f2bf(Whx[k * 512 + n]);
}

// ---------------------------------------------------------------------------
// Prep 1: W_hh [512,512] f32 -> WpkT [512 cols][256 pairs] u32
//         WpkT[j*256 + r] = pack_f16(W[2r][j], W[2r+1][j])  (col-major pairs)
// ---------------------------------------------------------------------------
__global__ void k_wpkT(const float* __restrict__ Whh, unsigned* __restrict__ WpkT) {
    int idx = blockIdx.x * 256 + threadIdx.x;     // 131072 total
    int j = idx >> 8;                             // 0..511 column
    int r = idx & 255;                            // 0..255 pair
    _Float16 lo = (_Float16)Whh[(2 * r) * 512 + j];
    _Float16 hi = (_Float16)Whh[(2 * r + 1) * 512 + j];
    WpkT[j * 256 + r] = (unsigned)__builtin_bit_cast(unsigned short, lo) |
                        ((unsigned)__builtin_bit_cast(unsigned short, hi) << 16);
}

// ---------------------------------------------------------------------------
// Phase 1: Z = x @ W_hx + b_h  ->  f16 Zh [T*B, H]
// ---------------------------------------------------------------------------
__global__ void __launch_bounds__(256) k_gemm1(const float* __restrict__ x,
                                               const unsigned short* __restrict__ WhxT,
                                               const float* __restrict__ bh,
                                               _Float16* __restrict__ Zh) {
    __shared__ unsigned short Asm[128 * 32];
    __shared__ unsigned short Bsm[128 * 32];
    const int tid = threadIdx.x;
    const int bid = blockIdx.x;
    const int nt = bid & 3, mt = bid >> 2;
    const int r0 = mt * 128, n0 = nt * 128;
    const int w  = tid >> 6, l = tid & 63;
    const int wm = (w >> 1) * 64, wn = (w & 1) * 64;
    const int lr = l & 15, lk = (l >> 4) * 8;

    const int arow = tid >> 2, akc = (tid & 3) * 8;
    const int bcol = tid >> 1, bkc = (tid & 1) * 16;

    f32x4 acc[4][4] = {};

    for (int kk = 0; kk < 256; kk += 32) {
#pragma unroll
        for (int half = 0; half < 2; ++half) {
            const int r = arow + half * 64;
            const float* ap = x + (size_t)(r0 + r) * 256 + kk + akc;
            float4 f0 = *(const float4*)ap;
            float4 f1 = *(const float4*)(ap + 4);
            uint4 av;
            av.x = (unsigned)f2bf(f0.x) | ((unsigned)f2bf(f0.y) << 16);
            av.y = (unsigned)f2bf(f0.z) | ((unsigned)f2bf(f0.w) << 16);
            av.z = (unsigned)f2bf(f1.x) | ((unsigned)f2bf(f1.y) << 16);
            av.w = (unsigned)f2bf(f1.z) | ((unsigned)f2bf(f1.w) << 16);
            *(uint4*)&Asm[r * 32 + akc] = av;
        }
        const unsigned short* bsrc = WhxT + (size_t)(n0 + bcol) * 256 + kk + bkc;
        uint4 bv0 = *(const uint4*)bsrc;
        uint4 bv1 = *(const uint4*)(bsrc + 8);
        *(uint4*)&Bsm[bcol * 32 + bkc] = bv0;
        *(uint4*)&Bsm[bcol * 32 + bkc + 8] = bv1;
        __syncthreads();

        s16x8 af[4], bf[4];
#pragma unroll
        for (int mi = 0; mi < 4; ++mi)
            af[mi] = *(const s16x8*)&Asm[(wm + mi * 16 + lr) * 32 + lk];
#pragma unroll
        for (int ni = 0; ni < 4; ++ni)
            bf[ni] = *(const s16x8*)&Bsm[(wn + ni * 16 + lr) * 32 + lk];
#pragma unroll
        for (int mi = 0; mi < 4; ++mi)
#pragma unroll
            for (int ni = 0; ni < 4; ++ni)
                acc[mi][ni] = __builtin_amdgcn_mfma_f32_16x16x32_bf16(af[mi], bf[ni], acc[mi][ni], 0, 0, 0);
        __syncthreads();
    }

#pragma unroll
    for (int mi = 0; mi < 4; ++mi)
#pragma unroll
        for (int ni = 0; ni < 4; ++ni) {
            int col = n0 + wn + ni * 16 + lr;
            float bhv = bh[col];
#pragma unroll
            for (int e = 0; e < 4; ++e) {
                int row = r0 + wm + mi * 16 + (l >> 4) * 4 + e;
                Zh[(size_t)row * 512 + col] = (_Float16)(acc[mi][ni][e] + bhv);
            }
        }
}

// ---------------------------------------------------------------------------
// Phase 2: recurrence. 128 WGs x 512 threads (thread = hidden column j).
// W_hh column j: 192 pairs in VGPRs, 64 pairs in LDS (interleaved 3:1 in the
// step body, with 1-iteration LDS prefetch). h double-buffered packed-f16 in
// LDS; ONE ds_read_b128/wave/step pulls all 256 pairs; broadcast by
// v_readlane -> SGPR operand of v_dot2_f32_f16. One barrier per step.
// __launch_bounds__(512,1): LDS (130KB) already forces 1 WG/CU; let the
// compiler use up to ~240 arch VGPRs so wreg[192] never spills.
// ---------------------------------------------------------------------------
__global__ void __launch_bounds__(512, 1) k_rnn(const unsigned* __restrict__ WpkT,
                                                const _Float16* __restrict__ Zh,
                                                float* __restrict__ hf) {
    __shared__ uint4    Wl4[NQ_LDS * 512];   // 128 KiB: weight groups [48,64)
    __shared__ unsigned hbuf[2][256];        // 2 KiB: h packed f16, double-buffered

    const int j = threadIdx.x;     // hidden column
    const int b = blockIdx.x;      // batch row
    const int l = j & 63;          // lane in wave

    const unsigned* wcol = WpkT + (size_t)j * 256;

    // ---- stationary weights: groups [0,48) -> 192 pairs in VGPRs ----
    v2h wreg[NQ_REG * 4];
#pragma unroll
    for (int g = 0; g < NQ_REG; ++g) {
        uint4 w = *(const uint4*)(wcol + g * 4);
        wreg[g * 4 + 0] = bc(w.x);
        wreg[g * 4 + 1] = bc(w.y);
        wreg[g * 4 + 2] = bc(w.z);
        wreg[g * 4 + 3] = bc(w.w);
    }
    // ---- groups [48,64) -> LDS ----
#pragma unroll
    for (int rb = 0; rb < NQ_LDS; ++rb)
        Wl4[rb * 512 + j] = *(const uint4*)(wcol + NQ_REG * 4 + rb * 4);

    ((_Float16*)hbuf[0])[j] = (_Float16)0.0f;   // h0 = 0
    __syncthreads();

    const _Float16* zrow = Zh + (size_t)b * H_ + j;   // T-step stride = B_*H_
    float zc = (float)zrow[0];
    float hv = 0.0f;
    int cur = 0;

    for (int t = 0; t < T_; ++t) {
        int tn = (t + 1 < T_) ? t + 1 : t;
        float zn = (float)zrow[(size_t)tn * (B_ * H_)];   // prefetch next z

        // one LDS read per wave: lane l gets h-pairs 4l..4l+3
        uint4 hv4 = ((const uint4*)hbuf[cur])[l];

        float a0 = 0.f, a1 = 0.f, a2 = 0.f, a3 = 0.f;
        uint4 w4 = Wl4[j];                                // prefetch LDS group 0
#pragma unroll
        for (int i = 0; i < NQ_LDS; ++i) {
            uint4 w4n;
            if (i + 1 < NQ_LDS) w4n = Wl4[(i + 1) * 512 + j];
#pragma unroll
            for (int k = 0; k < 3; ++k) {                 // 3 register groups
                const int q = i * 3 + k;                  // q in [0,48)
                a0 = dot2f(wreg[q * 4 + 0], rl(hv4.x, q), a0);
                a1 = dot2f(wreg[q * 4 + 1], rl(hv4.y, q), a1);
                a2 = dot2f(wreg[q * 4 + 2], rl(hv4.z, q), a2);
                a3 = dot2f(wreg[q * 4 + 3], rl(hv4.w, q), a3);
            }
            const int qL = NQ_REG + i;                    // 1 LDS group
            a0 = dot2f(bc(w4.x), rl(hv4.x, qL), a0);
            a1 = dot2f(bc(w4.y), rl(hv4.y, qL), a1);
            a2 = dot2f(bc(w4.z), rl(hv4.z, qL), a2);
            a3 = dot2f(bc(w4.w), rl(hv4.w, qL), a3);
            w4 = w4n;
        }
        float s = (a0 + a1) + (a2 + a3) + zc;
        float e = __expf(2.0f * s);                       // tanh via exp
        hv = 1.0f - 2.0f / (e + 1.0f);

        ((_Float16*)hbuf[cur ^ 1])[j] = (_Float16)hv;     // write new h to other buf
        __syncthreads();
        cur ^= 1;
        zc = zn;
    }
    hf[b * H_ + j] = hv;
}

// ---------------------------------------------------------------------------
// Phase 3: out = h_final @ W_ph + b_p   [128,512]@[512,10]
// ---------------------------------------------------------------------------
__global__ void k_out(const float* __restrict__ hf, const float* __restrict__ Wph,
                      const float* __restrict__ bp, float* __restrict__ out) {
    __shared__ float red[160];
    int b = blockIdx.x, t = threadIdx.x;
    if (t < 160) {
        int c = t >> 4, ks = (t & 15) * 32;
        float s = 0.f;
        for (int u = 0; u < 32; ++u)
            s += hf[b * H_ + ks + u] * Wph[(ks + u) * C_ + c];
        red[t] = s;
    }
    __syncthreads();
    if (t < C_) {
        float s = bp[t];
        for (int i = 0; i < 16; ++i) s += red[t * 16 + i];
        out[b * C_ + t] = s;
    }
}

// ---------------------------------------------------------------------------
extern "C" void kernel_launch(void* const* d_in, const int* in_sizes, int n_in,
                              void* d_out, int out_size, void* d_ws, size_t ws_size,
                              hipStream_t stream) {
    const float* x   = (const float*)d_in[0];
    const float* Whx = (const float*)d_in[1];
    const float* Whh = (const float*)d_in[2];
    const float* Wph = (const float*)d_in[3];
    const float* bh  = (const float*)d_in[4];
    const float* bp  = (const float*)d_in[5];
    float* out = (float*)d_out;

    char* ws = (char*)d_ws;
    unsigned short* WhxT = (unsigned short*)(ws);                    // 256 KiB
    unsigned*       WpkT = (unsigned*)(ws + 262144);                 // 512 KiB
    _Float16*       Zh   = (_Float16*)(ws + 786432);                 // 64 MiB
    float*          hf   = (float*)(ws + 786432 + 67108864);         // 256 KiB

    hipLaunchKernelGGL(k_whxT,  dim3(512),  dim3(256), 0, stream, Whx, WhxT);
    hipLaunchKernelGGL(k_wpkT,  dim3(512),  dim3(256), 0, stream, Whh, WpkT);
    hipLaunchKernelGGL(k_gemm1, dim3(2048), dim3(256), 0, stream, x, WhxT, bh, Zh);
    hipLaunchKernelGGL(k_rnn,   dim3(128),  dim3(512), 0, stream, WpkT, Zh, hf);
    hipLaunchKernelGGL(k_out,   dim3(128),  dim3(256), 0, stream, hf, Wph, bp, out);
}